// Round 10
// baseline (238.839 us; speedup 1.0000x reference)
//
#include <hip/hip_runtime.h>
#include <hip/hip_bf16.h>
#include <stdint.h>

// GroupCommunication fused: 65536 tok x 1024 ch; 16 blocks x 64; 2 heads x 32.
// R10: TT=16, 1024 thr (16 waves, ONE g per wave), 64KB static LDS ->
// 2 WGs/CU = 32 waves/CU (needs VGPR<=64: __launch_bounds__(1024,8); true
// live-set ~55). Head-sequential PH3-accumulate keeps att in a single 16KB
// buffer. Layout formulas = verified R9 kernel with the m-loop removed and
// t = g (wave id) in PH2.
// Schedule: PH1(0) |B| PH2(0)->att |B| accinit+PH3(0)+PH1(1) |B| PH2(1) |B|
//           PH3(1)+store.   (PH3 reads att; PH1 writes q/k/v -> same span OK)

typedef __attribute__((ext_vector_type(8))) short bf16x8;
typedef __attribute__((ext_vector_type(4))) float f32x4;

#define NTOK   65536
#define DM     1024
#define TT     16
#define QSCALE 0.17677669529663687f    // 32^-0.5
#define LOG2E  1.4426950408889634f

static __device__ __forceinline__ unsigned short f2bf(float f) {
  union { __hip_bfloat16 h; unsigned short s; } cv;
  cv.h = __float2bfloat16(f);          // RNE
  return cv.s;
}

static __device__ __forceinline__ unsigned int pk2(float a, float b) {
  return (unsigned int)f2bf(a) | ((unsigned int)f2bf(b) << 16);
}

static __device__ __forceinline__ bf16x8 pack8(float4 a, float4 b) {
  bf16x8 r;
  r[0] = (short)f2bf(a.x); r[1] = (short)f2bf(a.y);
  r[2] = (short)f2bf(a.z); r[3] = (short)f2bf(a.w);
  r[4] = (short)f2bf(b.x); r[5] = (short)f2bf(b.y);
  r[6] = (short)f2bf(b.z); r[7] = (short)f2bf(b.w);
  return r;
}

union FragCast { uint4 u4; bf16x8 v; uint2 u2[2]; unsigned int u[4]; };

// ---------------------------------------------------------------------------
// Prologue: pack wq(scaled),wk,wv,wf fp32 [g][i][o] -> bf16 fragment stream.
// frag elem j = W[k = kk*32 + 8*(lane>>4) + j][o = nf*16 + (lane&15)].
// A- and B-side consumers always use the identical (lane,j)->k map.
// ---------------------------------------------------------------------------
__global__ void build_wfrag(const float* __restrict__ wq, const float* __restrict__ wk,
                            const float* __restrict__ wv, const float* __restrict__ wf,
                            uint4* __restrict__ wfrag) {
  int tid = blockIdx.x * 256 + threadIdx.x;
  if (tid >= 4 * 16 * 2 * 4 * 64) return;
  int lane =  tid        & 63;
  int nf   = (tid >> 6)  & 3;
  int kk   = (tid >> 8)  & 1;
  int g    = (tid >> 9)  & 15;
  int mat  =  tid >> 13;
  const float* w = (mat == 0) ? wq : (mat == 1) ? wk : (mat == 2) ? wv : wf;
  float sc = (mat == 0) ? QSCALE : 1.0f;
  int o  = nf * 16 + (lane & 15);
  int kb = kk * 32 + 8 * (lane >> 4);
  unsigned int packed[4];
#pragma unroll
  for (int jj = 0; jj < 4; ++jj) {
    unsigned short lo = f2bf(w[(g * 64 + kb + 2 * jj    ) * 64 + o] * sc);
    unsigned short hi = f2bf(w[(g * 64 + kb + 2 * jj + 1) * 64 + o] * sc);
    packed[jj] = (unsigned int)lo | ((unsigned int)hi << 16);
  }
  uint4 u; u.x = packed[0]; u.y = packed[1]; u.z = packed[2]; u.w = packed[3];
  wfrag[tid] = u;
}

// ---------------------------------------------------------------------------
// Phase macros (h_/nf2_ literals; named frags only -> registers).
// ---------------------------------------------------------------------------

// q/k: swapped orientation. D[o][t]: col t = lr, rows o = nf*16+4lq+r.
#define QK_ONE(fA_, fB_, nf2_, h_, bp_, bsc_, dst_) do {                      \
  const int nf = 2 * (h_) + (nf2_);                                           \
  float4 b4 = *(const float4*)&(bp_)[g * 64 + nf * 16 + 4 * lq];              \
  f32x4 a1 = {b4.x * (bsc_), b4.y * (bsc_), b4.z * (bsc_), b4.w * (bsc_)};    \
  a1 = __builtin_amdgcn_mfma_f32_16x16x32_bf16((fA_).v, afr0, a1, 0, 0, 0);   \
  a1 = __builtin_amdgcn_mfma_f32_16x16x32_bf16((fB_).v, afr1, a1, 0, 0, 0);   \
  uint2 w2; w2.x = pk2(a1[0], a1[1]); w2.y = pk2(a1[2], a1[3]);               \
  const int blk = (16 * (2 * (nf2_) + (lq >> 1)) + g) ^ (lr & 7);             \
  *(uint2*)&(dst_)[lr * 512 + blk * 8 + 4 * (lq & 1)] = w2;                   \
} while (0)

// v: original orientation. D[t][o]: rows t = 4lq+r, col d_h = nf2*16+lr;
// stream pos encodes (f=g, d): pos = 64*(g>>2) + 4*d + (g&3).
#define V_ONE(fA_, fB_, nf2_, h_) do {                                        \
  const int nf = 2 * (h_) + (nf2_);                                           \
  const float bias = bv[g * 64 + nf * 16 + lr];                               \
  f32x4 a1 = {bias, bias, bias, bias};                                        \
  a1 = __builtin_amdgcn_mfma_f32_16x16x32_bf16(afr0, (fA_).v, a1, 0, 0, 0);   \
  a1 = __builtin_amdgcn_mfma_f32_16x16x32_bf16(afr1, (fB_).v, a1, 0, 0, 0);   \
  const int L = 16 * (g >> 2) + lr;                                           \
  const int jj = g & 3;                                                       \
  _Pragma("unroll")                                                           \
  for (int r = 0; r < 4; ++r)                                                 \
    s_v[((4 * lq + r) * 2 + (nf2_)) * 256 + L * 4 + jj] = f2bf(a1[r]);        \
} while (0)

#define PH1(h_) do {                                                          \
  {                                                                           \
    FragCast qa0, qb0, qa1, qb1;       /* q: [kk][nf2] */                     \
    qa0.u4 = wfrag[(((0 * 16 + g) * 2 + 0) * 4 + 2 * (h_)    ) * 64 + lane];  \
    qb0.u4 = wfrag[(((0 * 16 + g) * 2 + 0) * 4 + 2 * (h_) + 1) * 64 + lane];  \
    qa1.u4 = wfrag[(((0 * 16 + g) * 2 + 1) * 4 + 2 * (h_)    ) * 64 + lane];  \
    qb1.u4 = wfrag[(((0 * 16 + g) * 2 + 1) * 4 + 2 * (h_) + 1) * 64 + lane];  \
    QK_ONE(qa0, qa1, 0, h_, bq, QSCALE, s_q);                                 \
    QK_ONE(qb0, qb1, 1, h_, bq, QSCALE, s_q);                                 \
  }                                                                           \
  {                                                                           \
    FragCast ka0, kb0, ka1, kb1;                                              \
    ka0.u4 = wfrag[(((1 * 16 + g) * 2 + 0) * 4 + 2 * (h_)    ) * 64 + lane];  \
    kb0.u4 = wfrag[(((1 * 16 + g) * 2 + 0) * 4 + 2 * (h_) + 1) * 64 + lane];  \
    ka1.u4 = wfrag[(((1 * 16 + g) * 2 + 1) * 4 + 2 * (h_)    ) * 64 + lane];  \
    kb1.u4 = wfrag[(((1 * 16 + g) * 2 + 1) * 4 + 2 * (h_) + 1) * 64 + lane];  \
    QK_ONE(ka0, ka1, 0, h_, bk, 1.0f, s_k);                                   \
    QK_ONE(kb0, kb1, 1, h_, bk, 1.0f, s_k);                                   \
  }                                                                           \
  {                                                                           \
    FragCast va0, vb0, va1, vb1;                                              \
    va0.u4 = wfrag[(((2 * 16 + g) * 2 + 0) * 4 + 2 * (h_)    ) * 64 + lane];  \
    vb0.u4 = wfrag[(((2 * 16 + g) * 2 + 0) * 4 + 2 * (h_) + 1) * 64 + lane];  \
    va1.u4 = wfrag[(((2 * 16 + g) * 2 + 1) * 4 + 2 * (h_)    ) * 64 + lane];  \
    vb1.u4 = wfrag[(((2 * 16 + g) * 2 + 1) * 4 + 2 * (h_) + 1) * 64 + lane];  \
    V_ONE(va0, va1, 0, h_);                                                   \
    V_ONE(vb0, vb1, 1, h_);                                                   \
  }                                                                           \
} while (0)

// PH2: QK^T + softmax + PV for token t = g (wave id), current head.
#define PH2() do {                                                            \
  const int t = g;                                                            \
  f32x4 zero = {0.f, 0.f, 0.f, 0.f};                                          \
  FragCast qa, ka;                                                            \
  const int blk = lane ^ (t & 7);                                             \
  qa.u4 = *(const uint4*)&s_q[t * 512 + blk * 8];                             \
  ka.u4 = *(const uint4*)&s_k[t * 512 + blk * 8];                             \
  /* D[f][g]: col g=lr, rows f=4lq+r (K=32 = full head dim) */                \
  f32x4 sc4 = __builtin_amdgcn_mfma_f32_16x16x32_bf16(ka.v, qa.v, zero, 0, 0, 0); \
  float m = fmaxf(fmaxf(sc4[0], sc4[1]), fmaxf(sc4[2], sc4[3]));              \
  m = fmaxf(m, __shfl_xor(m, 16));                                            \
  m = fmaxf(m, __shfl_xor(m, 32));                                            \
  float p0 = exp2f((sc4[0] - m) * LOG2E);                                     \
  float p1 = exp2f((sc4[1] - m) * LOG2E);                                     \
  float p2 = exp2f((sc4[2] - m) * LOG2E);                                     \
  float p3 = exp2f((sc4[3] - m) * LOG2E);                                     \
  float s = p0 + p1 + p2 + p3;                                                \
  s += __shfl_xor(s, 16);                                                     \
  s += __shfl_xor(s, 32);                                                     \
  const float inv = __fdividef(1.0f, s);                                      \
  FragCast pa;                 /* P[g=lr][f=4lq+jj] at slots jj 0..3 */       \
  pa.u[0] = pk2(p0 * inv, p1 * inv);                                          \
  pa.u[1] = pk2(p2 * inv, p3 * inv);                                          \
  pa.u[2] = 0; pa.u[3] = 0;                                                   \
  FragCast va0, va1;           /* V[f=4lq+jj][d=nf*16+lr] at slots jj 0..3 */ \
  va0.u2[0] = *(const uint2*)&s_v[(t * 2 + 0) * 256 + lane * 4];              \
  va0.u[2] = 0; va0.u[3] = 0;                                                 \
  va1.u2[0] = *(const uint2*)&s_v[(t * 2 + 1) * 256 + lane * 4];              \
  va1.u[2] = 0; va1.u[3] = 0;                                                 \
  /* D[d][g]: col g=lr, rows d=nf*16+4lq+r */                                 \
  f32x4 oo0 = __builtin_amdgcn_mfma_f32_16x16x32_bf16(va0.v, pa.v, zero, 0, 0, 0); \
  f32x4 oo1 = __builtin_amdgcn_mfma_f32_16x16x32_bf16(va1.v, pa.v, zero, 0, 0, 0); \
  uint2 w20; w20.x = pk2(oo0[0], oo0[1]); w20.y = pk2(oo0[2], oo0[3]);        \
  const int ab0 = (16 * (0 + (lq >> 1)) + lr) ^ (t & 7);                      \
  *(uint2*)&s_att[t * 512 + ab0 * 8 + 4 * (lq & 1)] = w20;                    \
  uint2 w21; w21.x = pk2(oo1[0], oo1[1]); w21.y = pk2(oo1[2], oo1[3]);        \
  const int ab1 = (16 * (2 + (lq >> 1)) + lr) ^ (t & 7);                      \
  *(uint2*)&s_att[t * 512 + ab1 * 8 + 4 * (lq & 1)] = w21;                    \
} while (0)

// PH3(h): acc += wf(head h) x att. f-frags loaded at span start (latency
// hides under the co-scheduled PH1 of the other head / store).
#define PH3(h_) do {                                                          \
  FragCast f0, f1, f2, f3;                                                    \
  f0.u4 = wfrag[(((3 * 16 + g) * 2 + (h_)) * 4 + 0) * 64 + lane];             \
  f1.u4 = wfrag[(((3 * 16 + g) * 2 + (h_)) * 4 + 1) * 64 + lane];             \
  f2.u4 = wfrag[(((3 * 16 + g) * 2 + (h_)) * 4 + 2) * 64 + lane];             \
  f3.u4 = wfrag[(((3 * 16 + g) * 2 + (h_)) * 4 + 3) * 64 + lane];             \
  const int blk3 = (16 * lq + g) ^ (lr & 7);                                  \
  FragCast aa;                 /* att[t=lr][g][d_h=8lq+j] -> B[k][t] */       \
  aa.u4 = *(const uint4*)&s_att[lr * 512 + blk3 * 8];                         \
  acc0 = __builtin_amdgcn_mfma_f32_16x16x32_bf16(f0.v, aa.v, acc0, 0, 0, 0);  \
  acc1 = __builtin_amdgcn_mfma_f32_16x16x32_bf16(f1.v, aa.v, acc1, 0, 0, 0);  \
  acc2 = __builtin_amdgcn_mfma_f32_16x16x32_bf16(f2.v, aa.v, acc2, 0, 0, 0);  \
  acc3 = __builtin_amdgcn_mfma_f32_16x16x32_bf16(f3.v, aa.v, acc3, 0, 0, 0);  \
} while (0)

// ---------------------------------------------------------------------------
__global__ __launch_bounds__(1024, 8)
void fused_gc16(const float* __restrict__ x,
                const float* __restrict__ bq, const float* __restrict__ bk,
                const float* __restrict__ bv, const float* __restrict__ bfb,
                const uint4* __restrict__ wfrag,
                float* __restrict__ out) {
  // 64KB static LDS: q/k/att [16 t][64 blk x 16B] (blk key ^(t&7)); v stream.
  __shared__ __align__(16) unsigned short s_q  [16 * 512];
  __shared__ __align__(16) unsigned short s_k  [16 * 512];
  __shared__ __align__(16) unsigned short s_v  [16 * 2 * 256];
  __shared__ __align__(16) unsigned short s_att[16 * 512];

  const int tid  = threadIdx.x;
  const int g    = tid >> 6;      // 16 waves: wave = g (PH1/PH3) = token t (PH2)
  const int lane = tid & 63;
  const int lr   = lane & 15;
  const int lq   = lane >> 4;
  const long tok0 = (long)blockIdx.x * TT;

  // x fragments: token row lr, channel block g
  bf16x8 afr0, afr1;
  {
    const float* xr = x + (tok0 + lr) * DM + g * 64;
    afr0 = pack8(*(const float4*)(xr + 8 * lq), *(const float4*)(xr + 8 * lq + 4));
    afr1 = pack8(*(const float4*)(xr + 32 + 8 * lq), *(const float4*)(xr + 32 + 8 * lq + 4));
  }

  f32x4 acc0, acc1, acc2, acc3;   // final-linear accumulators (nf 0..3)

  PH1(0);
  __syncthreads();
  PH2();
  __syncthreads();
  // acc init with final bias; consume att(h0); build h1 q/k/v (distinct bufs)
  {
    float4 b0 = *(const float4*)&bfb[g * 64 +  0 + 4 * lq];
    float4 b1 = *(const float4*)&bfb[g * 64 + 16 + 4 * lq];
    float4 b2 = *(const float4*)&bfb[g * 64 + 32 + 4 * lq];
    float4 b3 = *(const float4*)&bfb[g * 64 + 48 + 4 * lq];
    acc0[0] = b0.x; acc0[1] = b0.y; acc0[2] = b0.z; acc0[3] = b0.w;
    acc1[0] = b1.x; acc1[1] = b1.y; acc1[2] = b1.z; acc1[3] = b1.w;
    acc2[0] = b2.x; acc2[1] = b2.y; acc2[2] = b2.z; acc2[3] = b2.w;
    acc3[0] = b3.x; acc3[1] = b3.y; acc3[2] = b3.z; acc3[3] = b3.w;
  }
  PH3(0);
  PH1(1);
  __syncthreads();
  PH2();
  __syncthreads();
  PH3(1);

  // store out: D[o][t] -> one float4 per nf
  {
    float* orow = out + (tok0 + lr) * DM + g * 64 + 4 * lq;
    float4 o4;
    o4.x = acc0[0]; o4.y = acc0[1]; o4.z = acc0[2]; o4.w = acc0[3];
    *(float4*)(orow +  0) = o4;
    o4.x = acc1[0]; o4.y = acc1[1]; o4.z = acc1[2]; o4.w = acc1[3];
    *(float4*)(orow + 16) = o4;
    o4.x = acc2[0]; o4.y = acc2[1]; o4.z = acc2[2]; o4.w = acc2[3];
    *(float4*)(orow + 32) = o4;
    o4.x = acc3[0]; o4.y = acc3[1]; o4.z = acc3[2]; o4.w = acc3[3];
    *(float4*)(orow + 48) = o4;
  }
}

// ---------------------------------------------------------------------------
extern "C" void kernel_launch(void* const* d_in, const int* in_sizes, int n_in,
                              void* d_out, int out_size, void* d_ws, size_t ws_size,
                              hipStream_t stream) {
  const float* x   = (const float*)d_in[0];
  const float* wq  = (const float*)d_in[1];
  const float* bq_ = (const float*)d_in[2];
  const float* wk  = (const float*)d_in[3];
  const float* bk_ = (const float*)d_in[4];
  const float* wv  = (const float*)d_in[5];
  const float* bv_ = (const float*)d_in[6];
  const float* wf  = (const float*)d_in[7];
  const float* bf_ = (const float*)d_in[8];
  (void)in_sizes; (void)n_in; (void)out_size; (void)ws_size;

  uint4* wfrag = (uint4*)d_ws;   // 4*16*2*4*64 frags * 16B = 512 KiB

  build_wfrag<<<128, 256, 0, stream>>>(wq, wk, wv, wf, wfrag);
  fused_gc16<<<NTOK / TT, 1024, 0, stream>>>(x, bq_, bk_, bv_, bf_, wfrag,
                                             (float*)d_out);
}